// Round 7
// baseline (603.394 us; speedup 1.0000x reference)
//
#include <hip/hip_runtime.h>
#include <math.h>

typedef __bf16 bf16x8 __attribute__((ext_vector_type(8)));
typedef float f32x16 __attribute__((ext_vector_type(16)));

#define NTOK 131072
#define HDIM 128
#define ODIM 128
#define NEXP 8

__device__ __forceinline__ unsigned short f2bf(float f){
  union { float f; unsigned u; } v; v.f = f;
  unsigned r = v.u + 0x7FFFu + ((v.u >> 16) & 1u);
  return (unsigned short)(r >> 16);
}

// ---------------------------------------------------------------------------
// Kernel 1: pack W. Layout: [ot(4)][e(8)][kt(8)][l(64)][j(8)] bf16.
// A-frag (v_mfma_f32_32x32x16_bf16): A[m=l&31][k=(l>>5)*8+j]; o = ot*32+(l&31);
// k_global = kt*16 + (l>>5)*8 + j. Bias NOT packed (epilogue handles it).
__global__ void pack_w(const float* __restrict__ we, unsigned short* __restrict__ pw){
  int f = blockIdx.x * 256 + threadIdx.x;       // 0..16383 (16B chunk id)
  int l  = f & 63;
  int kt = (f >> 6) & 7;
  int e  = (f >> 9) & 7;
  int ot = (f >> 12) & 3;
  int o = ot * 32 + (l & 31);
  int kbase = kt * 16 + ((l >> 5) << 3);
  unsigned short vals[8];
#pragma unroll
  for (int j = 0; j < 8; ++j)
    vals[j] = f2bf(we[(e * HDIM + kbase + j) * ODIM + o]);
  *(bf16x8*)(pw + (size_t)f * 8) = *(bf16x8*)vals;
}

// ---------------------------------------------------------------------------
// Kernel 2: gating + x->bf16-frag pack. 64 tokens/block, 256 threads.
// (unchanged from R5 — works, near its data floor)
__global__ void gating_pack(const float* __restrict__ x, const float* __restrict__ wg,
                            float* __restrict__ gates_t, unsigned short* __restrict__ xf){
  __shared__ float xs[64 * 128];   // [tok][f4-chunk c ^ (tok&7)] 32 KB
  __shared__ float wgl[128 * 8];   // 4 KB
  __shared__ float plg[64 * 36];   // [tok][q*8+e], stride 36 (pad) 9 KB
  int t = threadIdx.x;
  size_t tokbase = (size_t)blockIdx.x * 64;

  ((float4*)wgl)[t] = ((const float4*)wg)[t];
  {
    const float4* xsrc = (const float4*)(x + tokbase * HDIM);
#pragma unroll
    for (int i = 0; i < 8; ++i){
      int idx = i * 256 + t;
      int tok = idx >> 5, c = idx & 31;
      *(float4*)&xs[tok * 128 + ((c ^ (tok & 7)) << 2)] = xsrc[idx];
    }
  }
  __syncthreads();

  {
    int tok = t & 63, q = t >> 6;
    float lg[8];
#pragma unroll
    for (int e = 0; e < 8; ++e) lg[e] = 0.0f;
#pragma unroll
    for (int i = 0; i < 8; ++i){
      int c = q * 8 + i;
      float4 v = *(float4*)&xs[tok * 128 + ((c ^ (tok & 7)) << 2)];
      const float* wr = wgl + c * 32;
#pragma unroll
      for (int e = 0; e < 8; ++e)
        lg[e] += v.x * wr[e] + v.y * wr[8 + e] + v.z * wr[16 + e] + v.w * wr[24 + e];
    }
    *(float4*)&plg[tok * 36 + q * 8]     = make_float4(lg[0], lg[1], lg[2], lg[3]);
    *(float4*)&plg[tok * 36 + q * 8 + 4] = make_float4(lg[4], lg[5], lg[6], lg[7]);
  }
  __syncthreads();

  if (t < 64){
    float lg[8];
#pragma unroll
    for (int e = 0; e < 8; ++e)
      lg[e] = plg[t * 36 + e] + plg[t * 36 + 8 + e] + plg[t * 36 + 16 + e] + plg[t * 36 + 24 + e];
    int i1 = 0; float v1 = lg[0];
#pragma unroll
    for (int e = 1; e < 8; ++e) if (lg[e] > v1){ v1 = lg[e]; i1 = e; }
    int i2 = -1; float v2 = -3.4e38f;
#pragma unroll
    for (int e = 0; e < 8; ++e) if (e != i1 && lg[e] > v2){ v2 = lg[e]; i2 = e; }
    float ex = __expf(v2 - v1);
    float inv = 1.0f / (1.0f + ex);
#pragma unroll
    for (int e = 0; e < 8; ++e)
      gates_t[(size_t)e * NTOK + tokbase + t] = (e == i1) ? inv : ((e == i2) ? ex * inv : 0.0f);
  }

  {
    int tokL = t >> 2, q = t & 3;
    float4 cv[8];
#pragma unroll
    for (int i = 0; i < 8; ++i)
      cv[i] = *(float4*)&xs[tokL * 128 + (((q * 8 + i) ^ (tokL & 7)) << 2)];
    size_t tgG = (size_t)blockIdx.x * 2 + (tokL >> 5);
#pragma unroll
    for (int jb = 0; jb < 4; ++jb){
      int h0 = q * 32 + jb * 8;
      int kt = h0 >> 4;
      int lslot = (tokL & 31) + 32 * (jb & 1);
      float4 a = cv[2 * jb], b = cv[2 * jb + 1];
      unsigned long long lo = (unsigned long long)f2bf(a.x)
                            | ((unsigned long long)f2bf(a.y) << 16)
                            | ((unsigned long long)f2bf(a.z) << 32)
                            | ((unsigned long long)f2bf(a.w) << 48);
      unsigned long long hi = (unsigned long long)f2bf(b.x)
                            | ((unsigned long long)f2bf(b.y) << 16)
                            | ((unsigned long long)f2bf(b.z) << 32)
                            | ((unsigned long long)f2bf(b.w) << 48);
      unsigned long long* dst = (unsigned long long*)(xf + ((tgG * 8 + kt) * 64 + lslot) * 8);
      dst[0] = lo; dst[1] = hi;
    }
  }
}

// ---------------------------------------------------------------------------
// Kernel 3: BARRIER-FREE MFMA GEMM (R6 lesson: the barrier structure, not
// occupancy, capped MfmaUtil at 26%). Block: 1 o-tile (32 o's) x 1024 tokens.
// Full W for the o-tile (64 KB) + bias staged ONCE, one barrier, then each
// wave loops over 8 token-groups with zero synchronization: A/B register
// ping-pong prefetch (loads issued one full compute-iteration early),
// 2 independent 8-deep MFMA chains (e-pairs), gate combine, bias, store.
// LDS 65 KB -> 2 blocks/CU. Named regs / constant indices only (R1-R3 lesson).
__launch_bounds__(256, 2)
__global__ void moe_gemm(const unsigned short* __restrict__ pw,
                         const unsigned short* __restrict__ xf,
                         const float* __restrict__ gates_t,
                         const float* __restrict__ be, float* __restrict__ out){
  __shared__ unsigned short Wh[8 * 8 * 64 * 8];   // 64 KB: [e8][kt8][l64][j8]
  __shared__ float blds[256];                     //  1 KB: [e8][o32]

  int t = threadIdx.x;
  int ot = blockIdx.x & 3;
  int tb = blockIdx.x >> 2;              // 0..127
  int w = t >> 6, l = t & 63, l32 = l & 31, lh = l >> 5;
  size_t tgG0 = (size_t)tb * 32;         // 32 token-groups per block

  // stage full W o-tile slice + bias (coalesced), single barrier
  {
    const uint4* wsrc = (const uint4*)pw + (size_t)ot * 4096;
    uint4* wdst = (uint4*)Wh;
#pragma unroll
    for (int i = 0; i < 16; ++i)
      wdst[i * 256 + t] = wsrc[i * 256 + t];
  }
  blds[t] = be[(t >> 5) * ODIM + ot * 32 + (t & 31)];
  __syncthreads();

  f32x16 zero16;
#pragma unroll
  for (int i = 0; i < 16; ++i) zero16[i] = 0.0f;

#define LOADF(XB, G, TG)                                                        \
  {                                                                             \
    size_t tgG_ = tgG0 + (TG);                                                  \
    _Pragma("unroll")                                                           \
    for (int kt = 0; kt < 8; ++kt)                                              \
      XB[kt] = *(const bf16x8*)(xf + ((tgG_ * 8 + kt) * 64 + l) * 8);           \
    _Pragma("unroll")                                                           \
    for (int e = 0; e < 8; ++e)                                                 \
      G[e] = gates_t[(size_t)e * NTOK + tgG_ * 32 + l32];                       \
  }

#define COMPUTE_STORE(XB, G, TG)                                                \
  {                                                                             \
    f32x16 tot = zero16;                                                        \
    _Pragma("unroll")                                                           \
    for (int e = 0; e < 8; e += 2){                                             \
      f32x16 p0 = zero16, p1 = zero16;                                          \
      _Pragma("unroll")                                                         \
      for (int kt = 0; kt < 8; ++kt){                                           \
        bf16x8 a0 = *(const bf16x8*)&Wh[(((e + 0) * 8 + kt) * 64 + l) * 8];     \
        bf16x8 a1 = *(const bf16x8*)&Wh[(((e + 1) * 8 + kt) * 64 + l) * 8];     \
        p0 = __builtin_amdgcn_mfma_f32_32x32x16_bf16(a0, XB[kt], p0, 0, 0, 0);  \
        p1 = __builtin_amdgcn_mfma_f32_32x32x16_bf16(a1, XB[kt], p1, 0, 0, 0);  \
      }                                                                         \
      _Pragma("unroll")                                                         \
      for (int r = 0; r < 16; ++r)                                              \
        tot[r] += G[e] * p0[r] + G[e + 1] * p1[r];                              \
    }                                                                           \
    _Pragma("unroll")                                                           \
    for (int e = 0; e < 8; ++e){                                                \
      _Pragma("unroll")                                                         \
      for (int rg = 0; rg < 4; ++rg){                                           \
        float4 b4 = *(float4*)&blds[e * 32 + rg * 8 + lh * 4];                  \
        tot[rg * 4 + 0] += G[e] * b4.x; tot[rg * 4 + 1] += G[e] * b4.y;         \
        tot[rg * 4 + 2] += G[e] * b4.z; tot[rg * 4 + 3] += G[e] * b4.w;         \
      }                                                                         \
    }                                                                           \
    float* orow = out + ((tgG0 + (TG)) * 32 + l32) * ODIM + ot * 32;            \
    _Pragma("unroll")                                                           \
    for (int rg = 0; rg < 4; ++rg)                                              \
      *(float4*)(orow + rg * 8 + lh * 4) =                                      \
        make_float4(tot[rg * 4 + 0], tot[rg * 4 + 1],                           \
                    tot[rg * 4 + 2], tot[rg * 4 + 3]);                          \
  }

  // wave w handles tg = {it*4 + w : it 0..7}; A/B ping-pong, prefetch depth 1
  bf16x8 xbA[8], xbB[8];
  float gA[8], gB[8];
  LOADF(xbA, gA, w)                      // tg(it=0)
#pragma unroll 1
  for (int it2 = 0; it2 < 4; ++it2){
    int tgA = it2 * 8 + w;               // it = 2*it2
    int tgB = it2 * 8 + 4 + w;           // it = 2*it2 + 1
    LOADF(xbB, gB, tgB)
    COMPUTE_STORE(xbA, gA, tgA)
    int tgA2 = (it2 < 3) ? (it2 * 8 + 8 + w) : tgA;   // last iter: dummy reload
    LOADF(xbA, gA, tgA2)
    COMPUTE_STORE(xbB, gB, tgB)
  }
#undef LOADF
#undef COMPUTE_STORE
}

// ---------------------------------------------------------------------------
extern "C" void kernel_launch(void* const* d_in, const int* in_sizes, int n_in,
                              void* d_out, int out_size, void* d_ws, size_t ws_size,
                              hipStream_t stream){
  const float* x  = (const float*)d_in[0];
  const float* wg = (const float*)d_in[1];
  // d_in[2] = w_noise (inactive in eval mode)
  const float* we = (const float*)d_in[3];
  const float* be = (const float*)d_in[4];
  // d_in[5] = top_k (== 2, baked in)
  float* out = (float*)d_out;

  unsigned short* pw      = (unsigned short*)d_ws;                    // 256 KB
  float*          gates_t = (float*)((char*)d_ws + 262144);           // 4 MB
  unsigned short* xf      = (unsigned short*)((char*)d_ws + 4456448); // 32 MB

  pack_w     <<<64,   256, 0, stream>>>(we, pw);
  gating_pack<<<2048, 256, 0, stream>>>(x, wg, gates_t, xf);
  moe_gemm   <<<512,  256, 0, stream>>>(pw, xf, gates_t, be, out);
}

// Round 8
// 394.095 us; speedup vs baseline: 1.5311x; 1.5311x over previous
//
#include <hip/hip_runtime.h>
#include <math.h>

typedef __bf16 bf16x8 __attribute__((ext_vector_type(8)));
typedef float f32x16 __attribute__((ext_vector_type(16)));

#define NTOK 131072
#define HDIM 128
#define ODIM 128
#define NEXP 8

__device__ __forceinline__ unsigned short f2bf(float f){
  union { float f; unsigned u; } v; v.f = f;
  unsigned r = v.u + 0x7FFFu + ((v.u >> 16) & 1u);
  return (unsigned short)(r >> 16);
}

// ---------------------------------------------------------------------------
// Kernel 1: pack W. Layout: [ot(4)][e(8)][kt(8)][l(64)][j(8)] bf16.
// A-frag (v_mfma_f32_32x32x16_bf16): A[m=l&31][k=(l>>5)*8+j]; o = ot*32+(l&31);
// k_global = kt*16 + (l>>5)*8 + j. Bias NOT packed (epilogue handles it).
__global__ void pack_w(const float* __restrict__ we, unsigned short* __restrict__ pw){
  int f = blockIdx.x * 256 + threadIdx.x;       // 0..16383 (16B chunk id)
  int l  = f & 63;
  int kt = (f >> 6) & 7;
  int e  = (f >> 9) & 7;
  int ot = (f >> 12) & 3;
  int o = ot * 32 + (l & 31);
  int kbase = kt * 16 + ((l >> 5) << 3);
  unsigned short vals[8];
#pragma unroll
  for (int j = 0; j < 8; ++j)
    vals[j] = f2bf(we[(e * HDIM + kbase + j) * ODIM + o]);
  *(bf16x8*)(pw + (size_t)f * 8) = *(bf16x8*)vals;
}

// ---------------------------------------------------------------------------
// Kernel 2: gating + x->bf16-frag pack. 64 tokens/block, 256 threads.
// (unchanged since R5 — works, near its data floor)
__global__ void gating_pack(const float* __restrict__ x, const float* __restrict__ wg,
                            float* __restrict__ gates_t, unsigned short* __restrict__ xf){
  __shared__ float xs[64 * 128];   // [tok][f4-chunk c ^ (tok&7)] 32 KB
  __shared__ float wgl[128 * 8];   // 4 KB
  __shared__ float plg[64 * 36];   // [tok][q*8+e], stride 36 (pad) 9 KB
  int t = threadIdx.x;
  size_t tokbase = (size_t)blockIdx.x * 64;

  ((float4*)wgl)[t] = ((const float4*)wg)[t];
  {
    const float4* xsrc = (const float4*)(x + tokbase * HDIM);
#pragma unroll
    for (int i = 0; i < 8; ++i){
      int idx = i * 256 + t;
      int tok = idx >> 5, c = idx & 31;
      *(float4*)&xs[tok * 128 + ((c ^ (tok & 7)) << 2)] = xsrc[idx];
    }
  }
  __syncthreads();

  {
    int tok = t & 63, q = t >> 6;
    float lg[8];
#pragma unroll
    for (int e = 0; e < 8; ++e) lg[e] = 0.0f;
#pragma unroll
    for (int i = 0; i < 8; ++i){
      int c = q * 8 + i;
      float4 v = *(float4*)&xs[tok * 128 + ((c ^ (tok & 7)) << 2)];
      const float* wr = wgl + c * 32;
#pragma unroll
      for (int e = 0; e < 8; ++e)
        lg[e] += v.x * wr[e] + v.y * wr[8 + e] + v.z * wr[16 + e] + v.w * wr[24 + e];
    }
    *(float4*)&plg[tok * 36 + q * 8]     = make_float4(lg[0], lg[1], lg[2], lg[3]);
    *(float4*)&plg[tok * 36 + q * 8 + 4] = make_float4(lg[4], lg[5], lg[6], lg[7]);
  }
  __syncthreads();

  if (t < 64){
    float lg[8];
#pragma unroll
    for (int e = 0; e < 8; ++e)
      lg[e] = plg[t * 36 + e] + plg[t * 36 + 8 + e] + plg[t * 36 + 16 + e] + plg[t * 36 + 24 + e];
    int i1 = 0; float v1 = lg[0];
#pragma unroll
    for (int e = 1; e < 8; ++e) if (lg[e] > v1){ v1 = lg[e]; i1 = e; }
    int i2 = -1; float v2 = -3.4e38f;
#pragma unroll
    for (int e = 0; e < 8; ++e) if (e != i1 && lg[e] > v2){ v2 = lg[e]; i2 = e; }
    float ex = __expf(v2 - v1);
    float inv = 1.0f / (1.0f + ex);
#pragma unroll
    for (int e = 0; e < 8; ++e)
      gates_t[(size_t)e * NTOK + tokbase + t] = (e == i1) ? inv : ((e == i2) ? ex * inv : 0.0f);
  }

  {
    int tokL = t >> 2, q = t & 3;
    float4 cv[8];
#pragma unroll
    for (int i = 0; i < 8; ++i)
      cv[i] = *(float4*)&xs[tokL * 128 + (((q * 8 + i) ^ (tokL & 7)) << 2)];
    size_t tgG = (size_t)blockIdx.x * 2 + (tokL >> 5);
#pragma unroll
    for (int jb = 0; jb < 4; ++jb){
      int h0 = q * 32 + jb * 8;
      int kt = h0 >> 4;
      int lslot = (tokL & 31) + 32 * (jb & 1);
      float4 a = cv[2 * jb], b = cv[2 * jb + 1];
      unsigned long long lo = (unsigned long long)f2bf(a.x)
                            | ((unsigned long long)f2bf(a.y) << 16)
                            | ((unsigned long long)f2bf(a.z) << 32)
                            | ((unsigned long long)f2bf(a.w) << 48);
      unsigned long long hi = (unsigned long long)f2bf(b.x)
                            | ((unsigned long long)f2bf(b.y) << 16)
                            | ((unsigned long long)f2bf(b.z) << 32)
                            | ((unsigned long long)f2bf(b.w) << 48);
      unsigned long long* dst = (unsigned long long*)(xf + ((tgG * 8 + kt) * 64 + lslot) * 8);
      dst[0] = lo; dst[1] = hi;
    }
  }
}

// ---------------------------------------------------------------------------
// Kernel 3: barrier-free MFMA GEMM, SINGLE-buffered (R7 lesson: ping-pong
// doubled live x-frags -> 295 MB scratch spill; R6 lesson: per-K-loop barriers
// cap MfmaUtil at 26%). Block: 1 o-tile (32 o's) x 1024 tokens, 256 thr.
// Full W o-tile slice (64 KB) + bias staged once, ONE barrier, then each wave
// processes 8 token-groups independently: load xb[8]+gates, 4 e-pairs of dual
// 8-deep MFMA chains, gate-combine, bias epilogue (VALU, overlaps MFMA),
// coalesced store. Regs ~75 arch + 48 acc — inside the no-spill envelope.
// LDS 65 KB -> 2 blocks/CU; independent waves de-correlate stalls.
__launch_bounds__(256, 2)
__global__ void moe_gemm(const unsigned short* __restrict__ pw,
                         const unsigned short* __restrict__ xf,
                         const float* __restrict__ gates_t,
                         const float* __restrict__ be, float* __restrict__ out){
  __shared__ unsigned short Wh[8 * 8 * 64 * 8];   // 64 KB: [e8][kt8][l64][j8]
  __shared__ float blds[256];                     //  1 KB: [e8][o32]

  int t = threadIdx.x;
  int ot = blockIdx.x & 3;
  int tb = blockIdx.x >> 2;              // 0..127
  int w = t >> 6, l = t & 63, l32 = l & 31, lh = l >> 5;
  size_t tgG0 = (size_t)tb * 32;         // 32 token-groups per block

  // stage full W o-tile slice + bias (coalesced), single barrier
  {
    const uint4* wsrc = (const uint4*)pw + (size_t)ot * 4096;
    uint4* wdst = (uint4*)Wh;
#pragma unroll
    for (int i = 0; i < 16; ++i)
      wdst[i * 256 + t] = wsrc[i * 256 + t];
  }
  blds[t] = be[(t >> 5) * ODIM + ot * 32 + (t & 31)];
  __syncthreads();

  f32x16 zero16;
#pragma unroll
  for (int i = 0; i < 16; ++i) zero16[i] = 0.0f;

  // wave w handles tg = it*4 + w, it = 0..7 — no further synchronization.
#pragma unroll 1
  for (int it = 0; it < 8; ++it){
    size_t tgG = tgG0 + it * 4 + w;

    bf16x8 xb[8];
#pragma unroll
    for (int kt = 0; kt < 8; ++kt)
      xb[kt] = *(const bf16x8*)(xf + ((tgG * 8 + kt) * 64 + l) * 8);
    float g[8];
#pragma unroll
    for (int e = 0; e < 8; ++e)
      g[e] = gates_t[(size_t)e * NTOK + tgG * 32 + l32];

    f32x16 tot = zero16;
#pragma unroll
    for (int e = 0; e < 8; e += 2){
      f32x16 p0 = zero16, p1 = zero16;
#pragma unroll
      for (int kt = 0; kt < 8; ++kt){
        bf16x8 a0 = *(const bf16x8*)&Wh[(((e + 0) * 8 + kt) * 64 + l) * 8];
        bf16x8 a1 = *(const bf16x8*)&Wh[(((e + 1) * 8 + kt) * 64 + l) * 8];
        p0 = __builtin_amdgcn_mfma_f32_32x32x16_bf16(a0, xb[kt], p0, 0, 0, 0);
        p1 = __builtin_amdgcn_mfma_f32_32x32x16_bf16(a1, xb[kt], p1, 0, 0, 0);
      }
#pragma unroll
      for (int r = 0; r < 16; ++r)
        tot[r] += g[e] * p0[r] + g[e + 1] * p1[r];
    }

    // bias epilogue: tot += sum_e g[e] * b[e][o]  (VALU, overlaps MFMA pipe)
#pragma unroll
    for (int e = 0; e < 8; ++e){
#pragma unroll
      for (int rg = 0; rg < 4; ++rg){
        float4 b4 = *(float4*)&blds[e * 32 + rg * 8 + lh * 4];
        tot[rg * 4 + 0] += g[e] * b4.x; tot[rg * 4 + 1] += g[e] * b4.y;
        tot[rg * 4 + 2] += g[e] * b4.z; tot[rg * 4 + 3] += g[e] * b4.w;
      }
    }

    // C/D map: token(col)=l32, o = ot*32 + rg*8 + lh*4 + rr
    float* orow = out + (tgG * 32 + l32) * ODIM + ot * 32;
#pragma unroll
    for (int rg = 0; rg < 4; ++rg)
      *(float4*)(orow + rg * 8 + lh * 4) =
        make_float4(tot[rg * 4 + 0], tot[rg * 4 + 1], tot[rg * 4 + 2], tot[rg * 4 + 3]);
  }
}

// ---------------------------------------------------------------------------
extern "C" void kernel_launch(void* const* d_in, const int* in_sizes, int n_in,
                              void* d_out, int out_size, void* d_ws, size_t ws_size,
                              hipStream_t stream){
  const float* x  = (const float*)d_in[0];
  const float* wg = (const float*)d_in[1];
  // d_in[2] = w_noise (inactive in eval mode)
  const float* we = (const float*)d_in[3];
  const float* be = (const float*)d_in[4];
  // d_in[5] = top_k (== 2, baked in)
  float* out = (float*)d_out;

  unsigned short* pw      = (unsigned short*)d_ws;                    // 256 KB
  float*          gates_t = (float*)((char*)d_ws + 262144);           // 4 MB
  unsigned short* xf      = (unsigned short*)((char*)d_ws + 4456448); // 32 MB

  pack_w     <<<64,   256, 0, stream>>>(we, pw);
  gating_pack<<<2048, 256, 0, stream>>>(x, wg, gates_t, xf);
  moe_gemm   <<<512,  256, 0, stream>>>(pw, xf, gates_t, be, out);
}